// Round 1
// baseline (104.370 us; speedup 1.0000x reference)
//
#include <hip/hip_runtime.h>
#include <math.h>

#define B_ 8
#define P_ 32
#define S_ 512
#define D_ 64

typedef __attribute__((ext_vector_type(4))) _Float16 half4;
typedef __attribute__((ext_vector_type(4))) float f32x4;

// ---------------------------------------------------------------------------
// Fused kernel, query-split for occupancy. Grid 512 = 2 blocks per bp
// (half h = blockIdx>>8 so bp and bp+256 land on the same XCD slot),
// 512 threads (8 waves). Each block handles query tiles qt = 2*(wave+8i)+h,
// i<2  -> the two halves interleave tiles and together cover NQ <= 512.
//
// Math: out[s] = x[s] if mask[s]=1 else (sum_k P[s][k]*mask[k]*x[k] + x[s]) /
//       (sum_k P[s][k]*mask[k] + 1), P = exp(score-2), score = tpe_s . tpe_k,
//       self-weight exp(score_ss-2) = exp(0) = 1 exactly since |tpe|^2 = 2.
//
// Layout trick: compute S^T = mfma16(A=tpe_key-frag, B=tpe_query-frag).
// S^T C-layout (lane: col q = lane&15, rows key = quad*4+reg) IS the
// B-fragment layout of the PV mfma16 (lane: col q = lane&15, k = quad*4+j):
// P stays in registers. PV: inter^T = mfma16(A = fp16(mask*x)^T frag, B = P).
// Mask-row A-tile (ct=4, m=0 row = mask) makes the denominator fall out of
// the same MFMA chain. x staged to LDS once per block, double-buffered
// 64-key chunks. Key staging is duplicated across the 2 halves (shared-key
// algorithm), but those reads are L1/L2-resident for the second block.
// ---------------------------------------------------------------------------
__launch_bounds__(512, 2)
__global__ void k_fused(const float* __restrict__ t, const float* __restrict__ alpha_w,
                        const float* __restrict__ x, const float* __restrict__ mask,
                        float* __restrict__ out) {
    const int bp = blockIdx.x & (B_ * P_ - 1);
    const int h  = blockIdx.x >> 8;                 // query-half: 0 or 1
    const int b = bp >> 5;
    const int tid = threadIdx.x, lane = tid & 63, wave = tid >> 6;
    const int quad = lane >> 4, nl = lane & 15;

    __shared__ float maskL[S_];
    __shared__ short qidxL[S_];
    __shared__ int cntS;
    __shared__ float red[16];
    __shared__ __align__(16) _Float16 tpeP[S_][24];            // 24 KB (16 + 8 pad)
    __shared__ __align__(16) _Float16 Xfrag[2][4][5][64][4];   // 20 KB

    const float* maskBP = mask + (size_t)bp * S_;
    const float* xBP = x + (size_t)bp * S_ * D_;
    float* outBP = out + (size_t)bp * S_ * D_;

    // ---- load t + mask, min/max reduce ----
    float tv = t[b * S_ + tid];
    maskL[tid] = maskBP[tid];
    {
        float mn = tv, mx = tv;
#pragma unroll
        for (int o = 32; o > 0; o >>= 1) {
            mn = fminf(mn, __shfl_xor(mn, o, 64));
            mx = fmaxf(mx, __shfl_xor(mx, o, 64));
        }
        if (lane == 0) { red[wave] = mn; red[8 + wave] = mx; }
    }
    __syncthreads();   // B1
    float mn = red[0], mx = red[8];
#pragma unroll
    for (int w = 1; w < 8; w++) { mn = fminf(mn, red[w]); mx = fmaxf(mx, red[8 + w]); }

    float aw = alpha_w[0] * 1000.0f;
    float el = aw > 0.0f ? aw : (__expf(aw) - 1.0f);   // elu, alpha=1
    float inv = (el + 1.0f) / (mx - mn);

    // ---- tpe row tid (pre-scaled by 0.5 so dot = score/4) ----
    {
        const float divs[8] = {1.0f, 0.31622776601683794f, 0.1f, 0.031622776601683791f,
                               0.01f, 0.0031622776601683794f, 0.001f, 0.00031622776601683794f};
        float tn = (tv - mn) * inv;
        half4 w[4];
#pragma unroll
        for (int f = 0; f < 8; f++) {
            float ang = tn * divs[f];
            w[f >> 1][(f & 1) * 2]     = (_Float16)(0.5f * __sinf(ang));
            w[f >> 1][(f & 1) * 2 + 1] = (_Float16)(0.5f * __cosf(ang));
        }
#pragma unroll
        for (int g = 0; g < 4; g++) *(half4*)&tpeP[tid][g * 4] = w[g];
    }

    // ---- compacted query (mask=0) index list ----
    if (wave == 0) {
        int nq = 0;
        for (int c = 0; c < 8; c++) {
            int tt = c * 64 + lane;
            bool isq = maskL[tt] < 0.5f;
            unsigned long long bm = __ballot(isq);
            int pb = __popcll(bm & ((1ull << lane) - 1ull));
            if (isq) qidxL[nq + pb] = (short)tt;
            nq += __popcll(bm);
        }
        if (lane == 0) cntS = nq;
    }
    __syncthreads();   // B2
    const int NQ = cntS;

    // ---- per-wave query tiles: qt = 2*(wave + 8*i) + h, i<2 (NQ <= 512) ----
    bool act[2];
    half4 bQ[2];
#pragma unroll
    for (int i = 0; i < 2; i++) {
        int qt = 2 * (wave + 8 * i) + h;
        act[i] = (qt * 16) < NQ;
        int rq = act[i] ? min(qt * 16 + nl, NQ - 1) : 0;
        int row = ((int)qidxL[rq]) & (S_ - 1);
        bQ[i] = *(const half4*)&tpeP[row][quad * 4];
    }

    f32x4 acc[2][5];
#pragma unroll
    for (int i = 0; i < 2; i++)
#pragma unroll
        for (int ct = 0; ct < 5; ct++) acc[i][ct] = (f32x4){0.f, 0.f, 0.f, 0.f};

    // staging helpers: chunk = 64 keys = 4 kt-tiles of 16
    auto issue = [&](int kb, float v[2][4]) {
#pragma unroll
        for (int it = 0; it < 2; it++) {
            int item = it * 512 + tid;
            int d = item & 63, qd = (item >> 6) & 3, kt = (item >> 8) & 3;
            int key = kb + kt * 16 + qd * 4;
            const float* base = xBP + (size_t)key * D_ + d;
#pragma unroll
            for (int j = 0; j < 4; j++) v[it][j] = base[j * D_];
        }
    };
    auto commit = [&](int buf, int kb, float v[2][4]) {
#pragma unroll
        for (int it = 0; it < 2; it++) {
            int item = it * 512 + tid;
            int d = item & 63, qd = (item >> 6) & 3, kt = (item >> 8) & 3;
            int key = kb + kt * 16 + qd * 4;
            half4 w;
#pragma unroll
            for (int j = 0; j < 4; j++) {
                float mv = maskL[key + j];
                if (it == h && mv >= 0.5f)                       // copy rows: split by half
                    outBP[(size_t)(key + j) * D_ + d] = v[it][j];
                w[j] = (_Float16)(v[it][j] * mv);
            }
            *(half4*)&Xfrag[buf][kt][d >> 4][qd * 16 + (d & 15)][0] = w;
        }
        if (tid < 256) {   // mask A-tile (ct=4): row m=0 = mask, rows 1..15 = 0
            int kt = tid >> 6, l = tid & 63;
            int qd = l >> 4, m = l & 15;
            half4 w;
#pragma unroll
            for (int j = 0; j < 4; j++)
                w[j] = (m == 0) ? (_Float16)maskL[kb + kt * 16 + qd * 4 + j] : (_Float16)0.f;
            *(half4*)&Xfrag[buf][kt][4][l][0] = w;
        }
    };

    float v0[2][4];
    issue(0, v0);
    commit(0, 0, v0);
    __syncthreads();   // B3

    for (int c = 0; c < 8; c++) {
        float vn[2][4];
        if (c < 7) issue((c + 1) * 64, vn);

        const int buf = c & 1, kb = c * 64;
#pragma unroll
        for (int kt = 0; kt < 4; kt++) {
            half4 aK = *(const half4*)&tpeP[kb + kt * 16 + nl][quad * 4];
            half4 xA[5];
#pragma unroll
            for (int ct = 0; ct < 5; ct++)
                xA[ct] = *(const half4*)&Xfrag[buf][kt][ct][lane][0];
#pragma unroll
            for (int i = 0; i < 2; i++) {
                if (act[i]) {
                    f32x4 sT = __builtin_amdgcn_mfma_f32_16x16x16f16(
                        aK, bQ[i], (f32x4){0.f, 0.f, 0.f, 0.f}, 0, 0, 0);
                    half4 pt;
#pragma unroll
                    for (int j = 0; j < 4; j++) pt[j] = (_Float16)__expf(sT[j] - 2.0f);
#pragma unroll
                    for (int ct = 0; ct < 5; ct++)
                        acc[i][ct] = __builtin_amdgcn_mfma_f32_16x16x16f16(
                            xA[ct], pt, acc[i][ct], 0, 0, 0);
                }
            }
        }

        if (c < 7) commit(buf ^ 1, (c + 1) * 64, vn);
        __syncthreads();
    }

    // ---- epilogue: inter^T tiles (lane: col q = nl, rows d = quad*4+reg) ----
#pragma unroll
    for (int i = 0; i < 2; i++) {
        if (!act[i]) continue;
        int qt = 2 * (wave + 8 * i) + h;
        float den = __shfl(acc[i][4][0], nl, 64);   // D[m=0][q] from quad-0 lane
        float invd = 1.0f / (den + 1.0f);           // + self weight (exactly 1)
        int rowl = qt * 16 + nl;
        if (rowl < NQ) {
            int sg = qidxL[rowl];
#pragma unroll
            for (int ct = 0; ct < 4; ct++) {
                const float4 xv = *(const float4*)(xBP + (size_t)sg * D_ + ct * 16 + quad * 4);
                float4 o;
                o.x = (acc[i][ct][0] + xv.x) * invd;
                o.y = (acc[i][ct][1] + xv.y) * invd;
                o.z = (acc[i][ct][2] + xv.z) * invd;
                o.w = (acc[i][ct][3] + xv.w) * invd;
                *(float4*)(outBP + (size_t)sg * D_ + ct * 16 + quad * 4) = o;
            }
        }
    }
}

// ---------------------------------------------------------------------------
extern "C" void kernel_launch(void* const* d_in, const int* in_sizes, int n_in,
                              void* d_out, int out_size, void* d_ws, size_t ws_size,
                              hipStream_t stream) {
    const float* t       = (const float*)d_in[0]; // (B,S)
    const float* x       = (const float*)d_in[1]; // (B,P,S,D)
    const float* mask    = (const float*)d_in[2]; // (B,P,S)
    const float* alpha_w = (const float*)d_in[3]; // (1,1)
    float* out = (float*)d_out;

    k_fused<<<dim3(B_ * P_ * 2), dim3(512), 0, stream>>>(t, alpha_w, x, mask, out);
}

// Round 2
// 101.444 us; speedup vs baseline: 1.0288x; 1.0288x over previous
//
#include <hip/hip_runtime.h>
#include <math.h>

#define B_ 8
#define P_ 32
#define S_ 512
#define D_ 64

typedef __attribute__((ext_vector_type(4))) _Float16 half4;
typedef __attribute__((ext_vector_type(4))) float f32x4;

// ---------------------------------------------------------------------------
// Fused kernel, query-split + KEY-COMPACTED. Grid 512 = 2 blocks per bp
// (half h = blockIdx>>8), 512 threads (8 waves), forced 2 blocks/CU via
// __launch_bounds__(512,4) (4 waves/EU -> 16 waves/CU -> k=2 for 8-wave
// blocks; VGPR capped at 128).
//
// Math: out[s] = x[s] if mask[s]=1 else (sum_k P[s][k]*mask[k]*x[k] + x[s]) /
//       (sum_k P[s][k]*mask[k] + 1), P = exp(score-2), score = tpe_s . tpe_k,
//       self-weight exp(0) = 1 exactly since |tpe|^2 = 2.
//
// KEY COMPACTION: only mask=1 keys contribute (staged value is x*mask and the
// denominator row is mask). Build compacted key list kidxL (NK ~ S/2); stage
// and MFMA only those keys -> ~half the chunks, staging reads, MFMAs and
// barriers of the uncompacted version. Pad keys (>= NK) get zero weight in
// both the x-fragment and the mask A-row, so their P values multiply zero.
// Copy-rows (out = x for mask=1) are written during the compacted staging
// pass (split by half via it==h so stores aren't duplicated).
//
// Layout trick: compute S^T = mfma16(A=tpe_key-frag, B=tpe_query-frag).
// S^T C-layout (lane: col q = lane&15, rows key = quad*4+reg) IS the
// B-fragment layout of the PV mfma16: P stays in registers.
// PV: inter^T = mfma16(A = fp16(x_masked)^T frag, B = P). Mask-row A-tile
// (ct=4, m=0 row = key-valid) yields the denominator from the same MFMA chain.
// ---------------------------------------------------------------------------
__launch_bounds__(512, 4)
__global__ void k_fused(const float* __restrict__ t, const float* __restrict__ alpha_w,
                        const float* __restrict__ x, const float* __restrict__ mask,
                        float* __restrict__ out) {
    const int bp = blockIdx.x & (B_ * P_ - 1);
    const int h  = blockIdx.x >> 8;                 // query-half: 0 or 1
    const int b = bp >> 5;
    const int tid = threadIdx.x, lane = tid & 63, wave = tid >> 6;
    const int quad = lane >> 4, nl = lane & 15;

    __shared__ float maskL[S_];
    __shared__ short qidxL[S_];
    __shared__ short kidxL[S_];
    __shared__ int cntS[2];
    __shared__ float red[16];
    __shared__ __align__(16) _Float16 tpeP[S_][24];            // 24 KB (16 + 8 pad)
    __shared__ __align__(16) _Float16 Xfrag[2][4][5][64][4];   // 20 KB

    const float* maskBP = mask + (size_t)bp * S_;
    const float* xBP = x + (size_t)bp * S_ * D_;
    float* outBP = out + (size_t)bp * S_ * D_;

    // ---- load t + mask, min/max reduce ----
    float tv = t[b * S_ + tid];
    maskL[tid] = maskBP[tid];
    {
        float mn = tv, mx = tv;
#pragma unroll
        for (int o = 32; o > 0; o >>= 1) {
            mn = fminf(mn, __shfl_xor(mn, o, 64));
            mx = fmaxf(mx, __shfl_xor(mx, o, 64));
        }
        if (lane == 0) { red[wave] = mn; red[8 + wave] = mx; }
    }
    __syncthreads();   // B1
    float mn = red[0], mx = red[8];
#pragma unroll
    for (int w = 1; w < 8; w++) { mn = fminf(mn, red[w]); mx = fmaxf(mx, red[8 + w]); }

    float aw = alpha_w[0] * 1000.0f;
    float el = aw > 0.0f ? aw : (__expf(aw) - 1.0f);   // elu, alpha=1
    float inv = (el + 1.0f) / (mx - mn);

    // ---- tpe row tid (pre-scaled by 0.5 so dot = score/4) ----
    {
        const float divs[8] = {1.0f, 0.31622776601683794f, 0.1f, 0.031622776601683791f,
                               0.01f, 0.0031622776601683794f, 0.001f, 0.00031622776601683794f};
        float tn = (tv - mn) * inv;
        half4 w[4];
#pragma unroll
        for (int f = 0; f < 8; f++) {
            float ang = tn * divs[f];
            w[f >> 1][(f & 1) * 2]     = (_Float16)(0.5f * __sinf(ang));
            w[f >> 1][(f & 1) * 2 + 1] = (_Float16)(0.5f * __cosf(ang));
        }
#pragma unroll
        for (int g = 0; g < 4; g++) *(half4*)&tpeP[tid][g * 4] = w[g];
    }

    // ---- compacted query (mask=0) and key (mask=1) index lists ----
    if (wave == 0) {
        int nq = 0, nk = 0;
        for (int c = 0; c < 8; c++) {
            int tt = c * 64 + lane;
            bool isq = maskL[tt] < 0.5f;
            unsigned long long bm = __ballot(isq);
            int pb = __popcll(bm & ((1ull << lane) - 1ull));   // queries before lane
            if (isq) qidxL[nq + pb] = (short)tt;
            else     kidxL[nk + (lane - pb)] = (short)tt;      // keys before lane
            int nqc = __popcll(bm);
            nq += nqc;
            nk += 64 - nqc;
        }
        if (lane == 0) { cntS[0] = nq; cntS[1] = nk; }
    }
    __syncthreads();   // B2
    const int NQ = cntS[0];
    const int NK = cntS[1];
    const int NCH = (NK + 63) >> 6;

    // ---- per-wave query tiles: qt = 2*(wave + 8*i) + h, i<2 (NQ <= 512) ----
    bool act[2];
    half4 bQ[2];
#pragma unroll
    for (int i = 0; i < 2; i++) {
        int qt = 2 * (wave + 8 * i) + h;
        act[i] = (qt * 16) < NQ;
        int rq = act[i] ? min(qt * 16 + nl, NQ - 1) : 0;
        int row = ((int)qidxL[rq]) & (S_ - 1);
        bQ[i] = *(const half4*)&tpeP[row][quad * 4];
    }

    f32x4 acc[2][5];
#pragma unroll
    for (int i = 0; i < 2; i++)
#pragma unroll
        for (int ct = 0; ct < 5; ct++) acc[i][ct] = (f32x4){0.f, 0.f, 0.f, 0.f};

    // staging helpers: chunk = 64 compacted keys = 4 kt-tiles of 16
    auto issue = [&](int kb, float v[2][4]) {
#pragma unroll
        for (int it = 0; it < 2; it++) {
            int item = it * 512 + tid;
            int d = item & 63, qd = (item >> 6) & 3, kt = (item >> 8) & 3;
            int ki = kb + kt * 16 + qd * 4;
#pragma unroll
            for (int j = 0; j < 4; j++) {
                int key = (int)kidxL[min(ki + j, NK - 1)];
                v[it][j] = xBP[(size_t)key * D_ + d];
            }
        }
    };
    auto commit = [&](int buf, int kb, float v[2][4]) {
#pragma unroll
        for (int it = 0; it < 2; it++) {
            int item = it * 512 + tid;
            int d = item & 63, qd = (item >> 6) & 3, kt = (item >> 8) & 3;
            int ki = kb + kt * 16 + qd * 4;
            half4 w;
#pragma unroll
            for (int j = 0; j < 4; j++) {
                bool val = (ki + j) < NK;
                if (it == h && val)   // copy rows (mask=1): out = x, split by half
                    outBP[(size_t)((int)kidxL[ki + j]) * D_ + d] = v[it][j];
                w[j] = val ? (_Float16)v[it][j] : (_Float16)0.f;
            }
            *(half4*)&Xfrag[buf][kt][d >> 4][qd * 16 + (d & 15)][0] = w;
        }
        if (tid < 256) {   // valid-key A-tile (ct=4): row m=0 = 1 if key valid
            int kt = tid >> 6, l = tid & 63;
            int qd = l >> 4, m = l & 15;
            half4 w;
#pragma unroll
            for (int j = 0; j < 4; j++)
                w[j] = (m == 0 && (kb + kt * 16 + qd * 4 + j) < NK) ? (_Float16)1.f
                                                                    : (_Float16)0.f;
            *(half4*)&Xfrag[buf][kt][4][l][0] = w;
        }
    };

    float v0[2][4];
    if (NCH > 0) { issue(0, v0); commit(0, 0, v0); }
    __syncthreads();   // B3

    for (int c = 0; c < NCH; c++) {
        float vn[2][4];
        if (c + 1 < NCH) issue((c + 1) * 64, vn);

        const int buf = c & 1, kb = c * 64;
#pragma unroll
        for (int kt = 0; kt < 4; kt++) {
            int krow = (int)kidxL[min(kb + kt * 16 + nl, NK - 1)];
            half4 aK = *(const half4*)&tpeP[krow][quad * 4];
            half4 xA[5];
#pragma unroll
            for (int ct = 0; ct < 5; ct++)
                xA[ct] = *(const half4*)&Xfrag[buf][kt][ct][lane][0];
#pragma unroll
            for (int i = 0; i < 2; i++) {
                if (act[i]) {
                    f32x4 sT = __builtin_amdgcn_mfma_f32_16x16x16f16(
                        aK, bQ[i], (f32x4){0.f, 0.f, 0.f, 0.f}, 0, 0, 0);
                    half4 pt;
#pragma unroll
                    for (int j = 0; j < 4; j++) pt[j] = (_Float16)__expf(sT[j] - 2.0f);
#pragma unroll
                    for (int ct = 0; ct < 5; ct++)
                        acc[i][ct] = __builtin_amdgcn_mfma_f32_16x16x16f16(
                            xA[ct], pt, acc[i][ct], 0, 0, 0);
                }
            }
        }

        if (c + 1 < NCH) commit(buf ^ 1, (c + 1) * 64, vn);
        __syncthreads();
    }

    // ---- epilogue: inter^T tiles (lane: col q = nl, rows d = quad*4+reg) ----
#pragma unroll
    for (int i = 0; i < 2; i++) {
        if (!act[i]) continue;
        int qt = 2 * (wave + 8 * i) + h;
        float den = __shfl(acc[i][4][0], nl, 64);   // D[m=0][q] from quad-0 lane
        float invd = 1.0f / (den + 1.0f);           // + self weight (exactly 1)
        int rowl = qt * 16 + nl;
        if (rowl < NQ) {
            int sg = qidxL[rowl];
#pragma unroll
            for (int ct = 0; ct < 4; ct++) {
                const float4 xv = *(const float4*)(xBP + (size_t)sg * D_ + ct * 16 + quad * 4);
                float4 o;
                o.x = (acc[i][ct][0] + xv.x) * invd;
                o.y = (acc[i][ct][1] + xv.y) * invd;
                o.z = (acc[i][ct][2] + xv.z) * invd;
                o.w = (acc[i][ct][3] + xv.w) * invd;
                *(float4*)(outBP + (size_t)sg * D_ + ct * 16 + quad * 4) = o;
            }
        }
    }
}

// ---------------------------------------------------------------------------
extern "C" void kernel_launch(void* const* d_in, const int* in_sizes, int n_in,
                              void* d_out, int out_size, void* d_ws, size_t ws_size,
                              hipStream_t stream) {
    const float* t       = (const float*)d_in[0]; // (B,S)
    const float* x       = (const float*)d_in[1]; // (B,P,S,D)
    const float* mask    = (const float*)d_in[2]; // (B,P,S)
    const float* alpha_w = (const float*)d_in[3]; // (1,1)
    float* out = (float*)d_out;

    k_fused<<<dim3(B_ * P_ * 2), dim3(512), 0, stream>>>(t, alpha_w, x, mask, out);
}